// Round 1
// baseline (471.154 us; speedup 1.0000x reference)
//
#include <hip/hip_runtime.h>
#include <math.h>

#define NH 8
#define NL 4
#define NP 8
#define DHEAD 32
#define CDIM 256
#define NQ 10000
#define BS 2
#define NV 19560

__constant__ int LVL_H[NL]     = {92, 46, 23, 12};
__constant__ int LVL_W[NL]     = {160, 80, 40, 20};
__constant__ int LVL_START[NL] = {0, 14720, 18400, 19320};

// ---------------------------------------------------------------------------
// Tiled fp32 GEMM with bias: C[M,N] = A[M,K] @ B[K,N] + bias[N]
// 64x64 tile, 256 threads, 4x4 per thread, BK=16. N must be a multiple of 64,
// K a multiple of 16. M guarded.
// ---------------------------------------------------------------------------
__global__ __launch_bounds__(256) void gemm_bias_kernel(
    const float* __restrict__ A, const float* __restrict__ B,
    const float* __restrict__ bias, float* __restrict__ C,
    int M, int N, int K)
{
    __shared__ float As[16][64];   // [k][row]
    __shared__ float Bs[16][64];   // [k][col]

    const int t  = threadIdx.x;
    const int tx = t & 15;         // col group
    const int ty = t >> 4;         // row group
    const int rowBase = blockIdx.x * 64;
    const int colBase = blockIdx.y * 64;

    float acc[4][4] = {};

    for (int k0 = 0; k0 < K; k0 += 16) {
        // Load A tile (64 rows x 16 k), store transposed As[k][row]
        #pragma unroll
        for (int i = 0; i < 4; i++) {
            int e = t + i * 256;
            int r = e >> 4, c = e & 15;
            int row = rowBase + r;
            As[c][r] = (row < M) ? A[(size_t)row * K + k0 + c] : 0.f;
        }
        // Load B tile (16 k x 64 cols)
        #pragma unroll
        for (int i = 0; i < 4; i++) {
            int e = t + i * 256;
            int kk = e >> 6, cc = e & 63;
            Bs[kk][cc] = B[(size_t)(k0 + kk) * N + colBase + cc];
        }
        __syncthreads();

        #pragma unroll
        for (int kk = 0; kk < 16; kk++) {
            float4 a4 = *(const float4*)&As[kk][ty * 4];
            float4 b4 = *(const float4*)&Bs[kk][tx * 4];
            float av[4] = {a4.x, a4.y, a4.z, a4.w};
            float bv[4] = {b4.x, b4.y, b4.z, b4.w};
            #pragma unroll
            for (int i = 0; i < 4; i++)
                #pragma unroll
                for (int j = 0; j < 4; j++)
                    acc[i][j] += av[i] * bv[j];
        }
        __syncthreads();
    }

    #pragma unroll
    for (int i = 0; i < 4; i++) {
        int row = rowBase + ty * 4 + i;
        if (row >= M) continue;
        #pragma unroll
        for (int j = 0; j < 4; j++) {
            int col = colBase + tx * 4 + j;
            C[(size_t)row * N + col] = acc[i][j] + bias[col];
        }
    }
}

// ---------------------------------------------------------------------------
// Fused softmax + deformable sampling + aggregation.
// One block per (b, q). 256 threads.
// Phase A: thread t = (h = t/32, j = t%32, l = j/8, p = j%8) computes softmax
//          weight + 4 corner (index, weight) pairs into LDS.
// Phase B: thread t = (h = t/32, dch = t%32) accumulates over 32 points x 4
//          corners; value gathers are 32x4B = 128B coalesced per head group.
// ---------------------------------------------------------------------------
__global__ __launch_bounds__(256) void sample_kernel(
    const float* __restrict__ vproj,   // (BS, NV, 256)  [pix, h*32+d]
    const float* __restrict__ offbuf,  // (BS*NQ, 512)
    const float* __restrict__ attnbuf, // (BS*NQ, 256)
    const float* __restrict__ refpts,  // (BS, NQ, 4, 2)
    float* __restrict__ out)           // (BS*NQ, 256)
{
    const int qrow = blockIdx.x;       // b*NQ + q
    const int b    = qrow / NQ;
    const int t    = threadIdx.x;

    __shared__ int   s_idx[256][4];
    __shared__ float s_w[256][4];

    // ---------------- Phase A: weights + corner indices ----------------
    {
        const int h = t >> 5, j = t & 31, l = j >> 3, p = j & 7;

        // softmax over the 32 (l,p) logits of head h (lanes t in aligned
        // 32-lane groups)
        float logit = attnbuf[(size_t)qrow * 256 + t];
        float m = logit;
        #pragma unroll
        for (int s = 16; s > 0; s >>= 1) m = fmaxf(m, __shfl_xor(m, s, 32));
        float e = __expf(logit - m);
        float ssum = e;
        #pragma unroll
        for (int s = 16; s > 0; s >>= 1) ssum += __shfl_xor(ssum, s, 32);
        float aw = e / ssum;

        const int Wl = LVL_W[l], Hl = LVL_H[l], st = LVL_START[l];
        const size_t obase = (size_t)qrow * 512 + (size_t)(((h * NL + l) * NP + p) * 2);
        const float offx = offbuf[obase];
        const float offy = offbuf[obase + 1];

        const int z = p & 3;  // anchor index: NP split (NP//Z, Z), Z=4 inner
        const float* rp = refpts + ((size_t)qrow * 4 + z) * 2;
        const float locx = rp[0] + offx / (float)Wl;
        const float locy = rp[1] + offy / (float)Hl;

        const float x = locx * (float)Wl - 0.5f;
        const float y = locy * (float)Hl - 0.5f;
        const float x0f = floorf(x), y0f = floorf(y);
        const float wx = x - x0f, wy = y - y0f;
        const int x0 = (int)x0f, y0 = (int)y0f;

        const float cw[4] = {(1.f - wx) * (1.f - wy), wx * (1.f - wy),
                             (1.f - wx) * wy,         wx * wy};
        const int cx[4] = {x0, x0 + 1, x0, x0 + 1};
        const int cy[4] = {y0, y0,     y0 + 1, y0 + 1};

        #pragma unroll
        for (int c = 0; c < 4; c++) {
            const bool valid = (cx[c] >= 0) && (cx[c] < Wl) &&
                               (cy[c] >= 0) && (cy[c] < Hl);
            const int ix = min(max(cx[c], 0), Wl - 1);
            const int iy = min(max(cy[c], 0), Hl - 1);
            s_idx[t][c] = st + iy * Wl + ix;
            s_w[t][c]   = valid ? cw[c] * aw : 0.f;
        }
    }
    __syncthreads();

    // ---------------- Phase B: gather + accumulate ----------------
    const int h = t >> 5, dch = t & 31;
    const float* vb = vproj + (size_t)b * NV * 256 + h * 32 + dch;

    float acc = 0.f;
    #pragma unroll 4
    for (int j = 0; j < 32; j++) {
        const int e = h * 32 + j;
        #pragma unroll
        for (int c = 0; c < 4; c++) {
            const float w   = s_w[e][c];
            const int   idx = s_idx[e][c];
            acc += w * vb[(size_t)idx * 256];
        }
    }
    out[(size_t)qrow * 256 + t] = acc;
}

// ---------------------------------------------------------------------------
extern "C" void kernel_launch(void* const* d_in, const int* in_sizes, int n_in,
                              void* d_out, int out_size, void* d_ws, size_t ws_size,
                              hipStream_t stream)
{
    const float* query   = (const float*)d_in[0];  // (2, 10000, 256)
    const float* value   = (const float*)d_in[1];  // (2, 19560, 256)
    const float* refpts  = (const float*)d_in[2];  // (2, 10000, 4, 2)
    // d_in[3] spatial_shapes: static, hardcoded
    const float* W_value = (const float*)d_in[4];  // (256, 256)
    const float* b_value = (const float*)d_in[5];  // (256,)
    const float* W_off   = (const float*)d_in[6];  // (256, 512)
    const float* b_off   = (const float*)d_in[7];  // (512,)
    const float* W_attn  = (const float*)d_in[8];  // (256, 256)
    const float* b_attn  = (const float*)d_in[9];  // (256,)

    float* vproj = (float*)d_ws;                            // 2*19560*256
    float* offb  = vproj + (size_t)BS * NV * CDIM;          // 2*10000*512
    float* attnb = offb  + (size_t)BS * NQ * 512;           // 2*10000*256

    const dim3 blk(256);

    // value projection: (39120 x 256) @ (256 x 256)
    gemm_bias_kernel<<<dim3((BS * NV + 63) / 64, CDIM / 64), blk, 0, stream>>>(
        value, W_value, b_value, vproj, BS * NV, CDIM, CDIM);

    // offsets: (20000 x 256) @ (256 x 512)
    gemm_bias_kernel<<<dim3((BS * NQ + 63) / 64, 512 / 64), blk, 0, stream>>>(
        query, W_off, b_off, offb, BS * NQ, 512, CDIM);

    // attn logits: (20000 x 256) @ (256 x 256)
    gemm_bias_kernel<<<dim3((BS * NQ + 63) / 64, CDIM / 64), blk, 0, stream>>>(
        query, W_attn, b_attn, attnb, BS * NQ, CDIM, CDIM);

    // fused softmax + sampling + aggregation
    sample_kernel<<<dim3(BS * NQ), blk, 0, stream>>>(
        vproj, offb, attnb, refpts, (float*)d_out);
}

// Round 2
// 285.549 us; speedup vs baseline: 1.6500x; 1.6500x over previous
//
#include <hip/hip_runtime.h>
#include <math.h>

#define NH 8
#define NL 4
#define NP 8
#define CDIM 256
#define NQ 10000
#define BS 2
#define NV 19560

__constant__ int LVL_H[NL]     = {92, 46, 23, 12};
__constant__ int LVL_W[NL]     = {160, 80, 40, 20};
__constant__ int LVL_START[NL] = {0, 14720, 18400, 19320};

typedef __attribute__((ext_vector_type(8))) short short8;
typedef __attribute__((ext_vector_type(4))) float f32x4;

__device__ __forceinline__ unsigned short f2bf(float f) {
    unsigned int u = __float_as_uint(f);
    u += 0x7fffu + ((u >> 16) & 1u);   // RNE
    return (unsigned short)(u >> 16);
}

// ---------------------------------------------------------------------------
// bf16-MFMA GEMM with inline fp32->bf16 conversion in LDS staging.
// C[M,N] = A[M,256] @ B[256,N] + bias[N], fp32 out, fp32 accumulate.
// 128x128 block tile, 256 threads (4 waves, each 64x64 as 4x4 16x16 MFMA
// tiles), BK=32 (one mfma_f32_16x16x32_bf16 K-chunk per kg).
// LDS layout [kg][row][8k] -> fragment loads are aligned ds_read_b128 with
// exactly the A/B operand layout (lane l: m/n = l&15, k = (l>>4)*8 + e).
// Requires: K == 256, N % 128 == 0. M guarded.
// ---------------------------------------------------------------------------
__global__ __launch_bounds__(256) void gemm_bias_mfma(
    const float* __restrict__ A, const float* __restrict__ B,
    const float* __restrict__ bias, float* __restrict__ C,
    int M, int N)
{
    __shared__ short8 Al[4][128];
    __shared__ short8 Bl[4][128];

    const int t = threadIdx.x;
    const int rowBase = blockIdx.x * 128;
    const int colBase = blockIdx.y * 128;

    const int w  = t >> 6;            // wave 0..3
    const int l  = t & 63;
    const int wm = (w >> 1) * 64;     // wave row offset
    const int wn = (w & 1) * 64;      // wave col offset
    const int row16 = l & 15;
    const int kg    = l >> 4;         // 0..3

    // A staging mapping: thread covers (m = t>>1, k = akc..akc+15)
    const int am  = t >> 1;
    const int akc = (t & 1) * 16;
    // B staging mapping: thread covers (n = t&127, k = bk0 + {0..7, 16..23})
    const int bn  = t & 127;
    const int bk0 = (t >> 7) * 8;

    f32x4 acc[4][4] = {};

    for (int k0 = 0; k0 < 256; k0 += 32) {
        // ---- stage A (fp32 global -> bf16 LDS) ----
        {
            const int grow = rowBase + am;
            float va[16];
            if (grow < M) {
                const float* ap = A + (size_t)grow * 256 + k0 + akc;
                #pragma unroll
                for (int j = 0; j < 4; j++) {
                    float4 f = *(const float4*)(ap + j * 4);
                    va[j * 4 + 0] = f.x; va[j * 4 + 1] = f.y;
                    va[j * 4 + 2] = f.z; va[j * 4 + 3] = f.w;
                }
            } else {
                #pragma unroll
                for (int j = 0; j < 16; j++) va[j] = 0.f;
            }
            #pragma unroll
            for (int q = 0; q < 2; q++) {
                short8 v;
                #pragma unroll
                for (int e = 0; e < 8; e++) v[e] = (short)f2bf(va[q * 8 + e]);
                Al[(akc >> 3) + q][am] = v;
            }
        }
        // ---- stage B ----
        #pragma unroll
        for (int it = 0; it < 2; it++) {
            const int kk = bk0 + it * 16;
            const float* bp = B + (size_t)(k0 + kk) * N + colBase + bn;
            short8 v;
            #pragma unroll
            for (int j = 0; j < 8; j++) v[j] = (short)f2bf(bp[(size_t)j * N]);
            Bl[kk >> 3][bn] = v;
        }
        __syncthreads();

        // ---- MFMA ----
        short8 af[4], bf[4];
        #pragma unroll
        for (int i = 0; i < 4; i++) af[i] = Al[kg][wm + i * 16 + row16];
        #pragma unroll
        for (int j = 0; j < 4; j++) bf[j] = Bl[kg][wn + j * 16 + row16];
        #pragma unroll
        for (int i = 0; i < 4; i++)
            #pragma unroll
            for (int j = 0; j < 4; j++)
                acc[i][j] = __builtin_amdgcn_mfma_f32_16x16x32_bf16(
                    af[i], bf[j], acc[i][j], 0, 0, 0);
        __syncthreads();
    }

    // ---- epilogue: C/D layout col = l&15, row = (l>>4)*4 + reg ----
    const int crow0 = rowBase + wm + (l >> 4) * 4;
    const int ccol0 = colBase + wn + (l & 15);
    float bv[4];
    #pragma unroll
    for (int j = 0; j < 4; j++) bv[j] = bias[ccol0 + j * 16];
    #pragma unroll
    for (int i = 0; i < 4; i++) {
        #pragma unroll
        for (int r = 0; r < 4; r++) {
            const int row = crow0 + i * 16 + r;
            if (row < M) {
                #pragma unroll
                for (int j = 0; j < 4; j++)
                    C[(size_t)row * N + ccol0 + j * 16] = acc[i][j][r] + bv[j];
            }
        }
    }
}

// ---------------------------------------------------------------------------
// Fused softmax + deformable sampling + aggregation.
// One block per (b, q). 256 threads.
// Phase A: thread t = (h = t/32, l = (t%32)/8, p = t%8): softmax weight +
//          4 corner (index, weight) pairs into LDS (stride-5 padded).
// Phase B: t -> (h = t>>5, pp = (t>>3)&3, l8 = t&7): 4 channels per thread
//          (float4 = 16B; 8 lanes x 16B = one 128B line per gather), 4 points
//          in parallel across pp, then shfl_xor reduce over pp.
// ---------------------------------------------------------------------------
__global__ __launch_bounds__(256) void sample_kernel(
    const float* __restrict__ vproj,   // (BS, NV, 256)
    const float* __restrict__ offbuf,  // (BS*NQ, 512)
    const float* __restrict__ attnbuf, // (BS*NQ, 256)
    const float* __restrict__ refpts,  // (BS, NQ, 4, 2)
    float* __restrict__ out)           // (BS*NQ, 256)
{
    const int qrow = blockIdx.x;       // b*NQ + q
    const int b    = qrow / NQ;
    const int t    = threadIdx.x;

    __shared__ int   s_idx[256][5];    // stride-5 pad: parallel points hit
    __shared__ float s_w[256][5];      // distinct banks

    // ---------------- Phase A ----------------
    {
        const int h = t >> 5, j = t & 31, lv = j >> 3, p = j & 7;

        float logit = attnbuf[(size_t)qrow * 256 + t];
        float m = logit;
        #pragma unroll
        for (int s = 16; s > 0; s >>= 1) m = fmaxf(m, __shfl_xor(m, s, 32));
        float e = __expf(logit - m);
        float ssum = e;
        #pragma unroll
        for (int s = 16; s > 0; s >>= 1) ssum += __shfl_xor(ssum, s, 32);
        const float aw = e / ssum;

        const int Wl = LVL_W[lv], Hl = LVL_H[lv], st = LVL_START[lv];
        const size_t obase = (size_t)qrow * 512 + (size_t)(((h * NL + lv) * NP + p) * 2);
        const float offx = offbuf[obase];
        const float offy = offbuf[obase + 1];

        const int z = p & 3;           // anchor: NP split (NP//Z, Z), Z inner
        const float* rp = refpts + ((size_t)qrow * 4 + z) * 2;
        const float locx = rp[0] + offx / (float)Wl;
        const float locy = rp[1] + offy / (float)Hl;

        const float x = locx * (float)Wl - 0.5f;
        const float y = locy * (float)Hl - 0.5f;
        const float x0f = floorf(x), y0f = floorf(y);
        const float wx = x - x0f, wy = y - y0f;
        const int x0 = (int)x0f, y0 = (int)y0f;

        const float cw[4] = {(1.f - wx) * (1.f - wy), wx * (1.f - wy),
                             (1.f - wx) * wy,         wx * wy};
        const int cx[4] = {x0, x0 + 1, x0, x0 + 1};
        const int cy[4] = {y0, y0,     y0 + 1, y0 + 1};

        #pragma unroll
        for (int c = 0; c < 4; c++) {
            const bool valid = (cx[c] >= 0) && (cx[c] < Wl) &&
                               (cy[c] >= 0) && (cy[c] < Hl);
            const int ix = min(max(cx[c], 0), Wl - 1);
            const int iy = min(max(cy[c], 0), Hl - 1);
            s_idx[t][c] = st + iy * Wl + ix;
            s_w[t][c]   = valid ? cw[c] * aw : 0.f;
        }
    }
    __syncthreads();

    // ---------------- Phase B ----------------
    const int h  = t >> 5;
    const int pp = (t >> 3) & 3;       // parallel point group
    const int l8 = t & 7;              // channel quad
    const float* vb = vproj + (size_t)b * NV * 256 + h * 32 + l8 * 4;

    float4 acc = make_float4(0.f, 0.f, 0.f, 0.f);
    #pragma unroll 2
    for (int jj = 0; jj < 8; jj++) {
        const int e = h * 32 + pp * 8 + jj;
        #pragma unroll
        for (int c = 0; c < 4; c++) {
            const float w   = s_w[e][c];
            const int   idx = s_idx[e][c];
            const float4 v = *(const float4*)(vb + (size_t)idx * 256);
            acc.x += w * v.x; acc.y += w * v.y;
            acc.z += w * v.z; acc.w += w * v.w;
        }
    }

    // reduce across the 4 parallel point groups (lane bits 3,4 of 32-group)
    #pragma unroll
    for (int s = 8; s <= 16; s <<= 1) {
        acc.x += __shfl_xor(acc.x, s, 32);
        acc.y += __shfl_xor(acc.y, s, 32);
        acc.z += __shfl_xor(acc.z, s, 32);
        acc.w += __shfl_xor(acc.w, s, 32);
    }
    if (pp == 0)
        *(float4*)(out + (size_t)qrow * 256 + h * 32 + l8 * 4) = acc;
}

// ---------------------------------------------------------------------------
extern "C" void kernel_launch(void* const* d_in, const int* in_sizes, int n_in,
                              void* d_out, int out_size, void* d_ws, size_t ws_size,
                              hipStream_t stream)
{
    const float* query   = (const float*)d_in[0];  // (2, 10000, 256)
    const float* value   = (const float*)d_in[1];  // (2, 19560, 256)
    const float* refpts  = (const float*)d_in[2];  // (2, 10000, 4, 2)
    // d_in[3] spatial_shapes: static, hardcoded
    const float* W_value = (const float*)d_in[4];  // (256, 256)
    const float* b_value = (const float*)d_in[5];  // (256,)
    const float* W_off   = (const float*)d_in[6];  // (256, 512)
    const float* b_off   = (const float*)d_in[7];  // (512,)
    const float* W_attn  = (const float*)d_in[8];  // (256, 256)
    const float* b_attn  = (const float*)d_in[9];  // (256,)

    float* vproj = (float*)d_ws;                            // 2*19560*256
    float* offb  = vproj + (size_t)BS * NV * CDIM;          // 2*10000*512
    float* attnb = offb  + (size_t)BS * NQ * 512;           // 2*10000*256

    const dim3 blk(256);

    // value projection: (39120 x 256) @ (256 x 256)
    gemm_bias_mfma<<<dim3((BS * NV + 127) / 128, CDIM / 128), blk, 0, stream>>>(
        value, W_value, b_value, vproj, BS * NV, CDIM);

    // offsets: (20000 x 256) @ (256 x 512)
    gemm_bias_mfma<<<dim3((BS * NQ + 127) / 128, 512 / 128), blk, 0, stream>>>(
        query, W_off, b_off, offb, BS * NQ, 512);

    // attn logits: (20000 x 256) @ (256 x 256)
    gemm_bias_mfma<<<dim3((BS * NQ + 127) / 128, CDIM / 128), blk, 0, stream>>>(
        query, W_attn, b_attn, attnb, BS * NQ, CDIM);

    // fused softmax + sampling + aggregation
    sample_kernel<<<dim3(BS * NQ), blk, 0, stream>>>(
        vproj, offb, attnb, refpts, (float*)d_out);
}

// Round 3
// 227.750 us; speedup vs baseline: 2.0687x; 1.2538x over previous
//
#include <hip/hip_runtime.h>
#include <math.h>

#define NH 8
#define NL 4
#define NP 8
#define CDIM 256
#define NQ 10000
#define BS 2
#define NV 19560

__constant__ int LVL_H[NL]     = {92, 46, 23, 12};
__constant__ int LVL_W[NL]     = {160, 80, 40, 20};
__constant__ int LVL_START[NL] = {0, 14720, 18400, 19320};

typedef __attribute__((ext_vector_type(8))) short short8;
typedef __attribute__((ext_vector_type(4))) float f32x4;

__device__ __forceinline__ unsigned short f2bf(float f) {
    unsigned int u = __float_as_uint(f);
    u += 0x7fffu + ((u >> 16) & 1u);   // RNE
    return (unsigned short)(u >> 16);
}

// ---------------------------------------------------------------------------
// Concat W_off|W_attn -> Bcat (256x768) and b_off|b_attn -> bias_cat (768).
// ---------------------------------------------------------------------------
__global__ __launch_bounds__(256) void concat_wb(
    const float* __restrict__ W_off, const float* __restrict__ b_off,
    const float* __restrict__ W_attn, const float* __restrict__ b_attn,
    float* __restrict__ Bcat, float* __restrict__ bias_cat)
{
    const int k = blockIdx.x;          // 0..256 (256 == bias row)
    const int t = threadIdx.x;
    #pragma unroll
    for (int s = 0; s < 3; s++) {
        const int n = s * 256 + t;
        float v;
        if (k < 256)
            v = (n < 512) ? W_off[k * 512 + n] : W_attn[k * 256 + (n - 512)];
        else
            v = (n < 512) ? b_off[n] : b_attn[n - 512];
        if (k < 256) Bcat[k * 768 + n] = v;
        else         bias_cat[n] = v;
    }
}

// ---------------------------------------------------------------------------
// bf16-MFMA GEMM, inline fp32->bf16 staging. 128x128 tile, 256 thr, BK=32.
// LDS stride padded to 130 short8 to break staging write conflicts.
// MODE 0: C[M,N] fp32 = A@B + bias.
// MODE 1: value projection -> bf16 head-major vproj (b, h, pix, 32).
// ---------------------------------------------------------------------------
#define AST 130
template <int MODE>
__global__ __launch_bounds__(256) void gemm_bias_mfma(
    const float* __restrict__ A, const float* __restrict__ B,
    const float* __restrict__ bias, float* __restrict__ Cf,
    unsigned short* __restrict__ Cbf, int M, int N)
{
    __shared__ short8 Al[4 * AST];
    __shared__ short8 Bl[4 * AST];

    const int t = threadIdx.x;
    const int rowBase = blockIdx.x * 128;
    const int colBase = blockIdx.y * 128;

    const int w  = t >> 6;            // wave 0..3
    const int l  = t & 63;
    const int wm = (w >> 1) * 64;
    const int wn = (w & 1) * 64;
    const int row16 = l & 15;
    const int kg    = l >> 4;

    // A staging: thread covers (row r2 + 64*pass, kg = t&3, 8 k) = 32B load
    const int ar  = t >> 2;
    const int akg = t & 3;
    // B staging: col = t&127, two kgs (t>>7)*2 + {0,1}
    const int bn   = t & 127;
    const int bkg0 = (t >> 7) * 2;

    f32x4 acc[4][4] = {};

    for (int k0 = 0; k0 < 256; k0 += 32) {
        #pragma unroll
        for (int pass = 0; pass < 2; pass++) {
            const int r = pass * 64 + ar;
            const int grow = rowBase + r;
            float va[8];
            if (grow < M) {
                const float* ap = A + (size_t)grow * 256 + k0 + akg * 8;
                float4 f0 = *(const float4*)ap;
                float4 f1 = *(const float4*)(ap + 4);
                va[0]=f0.x; va[1]=f0.y; va[2]=f0.z; va[3]=f0.w;
                va[4]=f1.x; va[5]=f1.y; va[6]=f1.z; va[7]=f1.w;
            } else {
                #pragma unroll
                for (int e = 0; e < 8; e++) va[e] = 0.f;
            }
            short8 v;
            #pragma unroll
            for (int e = 0; e < 8; e++) v[e] = (short)f2bf(va[e]);
            Al[akg * AST + r] = v;
        }
        #pragma unroll
        for (int it = 0; it < 2; it++) {
            const int kgc = bkg0 + it;
            const float* bp = B + (size_t)(k0 + kgc * 8) * N + colBase + bn;
            short8 v;
            #pragma unroll
            for (int e = 0; e < 8; e++) v[e] = (short)f2bf(bp[(size_t)e * N]);
            Bl[kgc * AST + bn] = v;
        }
        __syncthreads();

        short8 af[4], bfr[4];
        #pragma unroll
        for (int i = 0; i < 4; i++) af[i] = Al[kg * AST + wm + i * 16 + row16];
        #pragma unroll
        for (int j = 0; j < 4; j++) bfr[j] = Bl[kg * AST + wn + j * 16 + row16];
        #pragma unroll
        for (int i = 0; i < 4; i++)
            #pragma unroll
            for (int j = 0; j < 4; j++)
                acc[i][j] = __builtin_amdgcn_mfma_f32_16x16x32_bf16(
                    af[i], bfr[j], acc[i][j], 0, 0, 0);
        __syncthreads();
    }

    // epilogue: C/D layout col = l&15, row = (l>>4)*4 + reg
    const int crow0 = rowBase + wm + (l >> 4) * 4;
    const int ccol0 = colBase + wn + (l & 15);
    float bv[4];
    #pragma unroll
    for (int j = 0; j < 4; j++) bv[j] = bias[ccol0 + j * 16];
    #pragma unroll
    for (int i = 0; i < 4; i++) {
        #pragma unroll
        for (int r = 0; r < 4; r++) {
            const int row = crow0 + i * 16 + r;
            if (row >= M) continue;
            #pragma unroll
            for (int j = 0; j < 4; j++) {
                const float val = acc[i][j][r] + bv[j];
                const int col = ccol0 + j * 16;
                if (MODE == 0) {
                    Cf[(size_t)row * N + col] = val;
                } else {
                    const int b   = row / NV;
                    const int pix = row - b * NV;
                    const int h   = col >> 5;
                    const int ch  = col & 31;
                    Cbf[((size_t)(b * NH + h) * NV + pix) * 32 + ch] = f2bf(val);
                }
            }
        }
    }
}

// ---------------------------------------------------------------------------
// Fused softmax + sampling + aggregation, (b,h)-partitioned for L2 locality.
// Block -> (h = blockIdx&7 [XCD swizzle], b, 8 queries). 256 threads.
// Phase A: t = (qi = t>>5, j = t&31 -> level, point): softmax + 2 row-pair
//          descriptors {pixel idx @xb, wL, wR} (x-corners fused; clamp edge
//          cases folded into the column weights).
// Phase B: 32 lanes/query: grp = lane>>3 strides descriptors, pix = bit2,
//          chq = lane&3 -> 8 bf16 channels (16 B load = half a 128 B
//          contiguous x-pair row). shfl_xor reduce over bits 2,3,4.
// ---------------------------------------------------------------------------
__global__ __launch_bounds__(256) void sample_kernel(
    const unsigned short* __restrict__ vproj, // (BS, NH, NV, 32) bf16
    const float* __restrict__ offcat,         // (BS*NQ, 768) off|logits
    const float* __restrict__ refpts,         // (BS, NQ, 4, 2)
    float* __restrict__ out)                  // (BS*NQ, 256)
{
    const int bid = blockIdx.x;
    const int h   = bid & 7;                  // XCD-affine head
    const int g   = bid >> 3;
    const int b   = g & 1;
    const int q0  = (g >> 1) * 8;
    const int t   = threadIdx.x;

    __shared__ float4 desc[8 * 64];           // {idx(bits), wL, wR, pad}

    const int qi = t >> 5, j = t & 31;
    const int qrow = b * NQ + q0 + qi;

    // ---------------- Phase A ----------------
    {
        const int lv = j >> 3, p = j & 7;

        float logit = offcat[(size_t)qrow * 768 + 512 + h * 32 + j];
        float m = logit;
        #pragma unroll
        for (int s = 16; s > 0; s >>= 1) m = fmaxf(m, __shfl_xor(m, s, 32));
        float e = __expf(logit - m);
        float ssum = e;
        #pragma unroll
        for (int s = 16; s > 0; s >>= 1) ssum += __shfl_xor(ssum, s, 32);
        const float aw = e / ssum;

        const int Wl = LVL_W[lv], Hl = LVL_H[lv], st = LVL_START[lv];
        const float offx = offcat[(size_t)qrow * 768 + h * 64 + j * 2];
        const float offy = offcat[(size_t)qrow * 768 + h * 64 + j * 2 + 1];

        const int z = p & 3;
        const float rx = refpts[((size_t)qrow * 4 + z) * 2];
        const float ry = refpts[((size_t)qrow * 4 + z) * 2 + 1];

        const float x = fmaf(rx, (float)Wl, offx) - 0.5f;
        const float y = fmaf(ry, (float)Hl, offy) - 0.5f;
        const float x0f = floorf(x), y0f = floorf(y);
        const float wx = x - x0f, wy = y - y0f;
        const int x0 = (int)x0f, y0 = (int)y0f;

        const int xb = min(max(x0, 0), Wl - 2);
        const float wl = (x0 >= 0 && x0 < Wl)          ? (1.f - wx) : 0.f;
        const float wr = (x0 + 1 >= 0 && x0 + 1 < Wl)  ? wx         : 0.f;
        // remap to columns xb, xb+1 (handles clamped edges; OOB weights are 0)
        const float wA = (x0 == xb) ? wl : ((x0 + 1 == xb) ? wr : 0.f);
        const float wB = (x0 == xb) ? wr : ((x0 == xb + 1) ? wl : 0.f);

        #pragma unroll
        for (int r = 0; r < 2; r++) {
            const int yy = y0 + r;
            const float rwv = (yy >= 0 && yy < Hl)
                            ? (r ? wy : (1.f - wy)) * aw : 0.f;
            const int iy = min(max(yy, 0), Hl - 1);
            float4 d;
            d.x = __int_as_float(st + iy * Wl + xb);
            d.y = wA * rwv;
            d.z = wB * rwv;
            d.w = 0.f;
            desc[qi * 64 + j * 2 + r] = d;
        }
    }
    __syncthreads();

    // ---------------- Phase B ----------------
    const int lane = t & 31;
    const int grp  = lane >> 3;               // descriptor stride group
    const int sub  = lane & 7;
    const int pix  = sub >> 2;                // left/right x-column
    const int chq  = sub & 3;                 // channel quad (8 ch)

    const uint* slab = (const uint*)(vproj + (size_t)(b * NH + h) * NV * 32);
    const float4* dq = &desc[qi * 64];

    float acc[8] = {};
    #pragma unroll 4
    for (int i = 0; i < 16; i++) {
        const float4 dsc = dq[i * 4 + grp];
        const int   lidx = __float_as_int(dsc.x);
        const float w    = pix ? dsc.z : dsc.y;
        const uint4 v = *(const uint4*)(slab + (size_t)(lidx + pix) * 16 + chq * 4);
        acc[0] += w * __uint_as_float(v.x << 16);
        acc[1] += w * __uint_as_float(v.x & 0xffff0000u);
        acc[2] += w * __uint_as_float(v.y << 16);
        acc[3] += w * __uint_as_float(v.y & 0xffff0000u);
        acc[4] += w * __uint_as_float(v.z << 16);
        acc[5] += w * __uint_as_float(v.z & 0xffff0000u);
        acc[6] += w * __uint_as_float(v.w << 16);
        acc[7] += w * __uint_as_float(v.w & 0xffff0000u);
    }

    #pragma unroll
    for (int s = 4; s <= 16; s <<= 1)
        #pragma unroll
        for (int e = 0; e < 8; e++) acc[e] += __shfl_xor(acc[e], s, 32);

    if ((lane & 0x1C) == 0) {                 // lanes 0..3 = chq
        float* op = out + (size_t)qrow * 256 + h * 32 + chq * 8;
        *(float4*)op       = make_float4(acc[0], acc[1], acc[2], acc[3]);
        *(float4*)(op + 4) = make_float4(acc[4], acc[5], acc[6], acc[7]);
    }
}

// ---------------------------------------------------------------------------
extern "C" void kernel_launch(void* const* d_in, const int* in_sizes, int n_in,
                              void* d_out, int out_size, void* d_ws, size_t ws_size,
                              hipStream_t stream)
{
    const float* query   = (const float*)d_in[0];
    const float* value   = (const float*)d_in[1];
    const float* refpts  = (const float*)d_in[2];
    const float* W_value = (const float*)d_in[4];
    const float* b_value = (const float*)d_in[5];
    const float* W_off   = (const float*)d_in[6];
    const float* b_off   = (const float*)d_in[7];
    const float* W_attn  = (const float*)d_in[8];
    const float* b_attn  = (const float*)d_in[9];

    unsigned short* vproj = (unsigned short*)d_ws;              // 20.03 MB bf16
    float* offcat  = (float*)((char*)d_ws + 20029440);          // 61.44 MB
    float* Bcat    = (float*)((char*)d_ws + 20029440 + 61440000);
    float* biascat = Bcat + 256 * 768;

    const dim3 blk(256);

    concat_wb<<<dim3(257), blk, 0, stream>>>(W_off, b_off, W_attn, b_attn,
                                             Bcat, biascat);

    // value projection -> bf16 head-major vproj
    gemm_bias_mfma<1><<<dim3((BS * NV + 127) / 128, 2), blk, 0, stream>>>(
        value, W_value, b_value, nullptr, vproj, BS * NV, CDIM);

    // fused offsets+logits: (20000 x 256) @ (256 x 768)
    gemm_bias_mfma<0><<<dim3((BS * NQ + 127) / 128, 6), blk, 0, stream>>>(
        query, Bcat, biascat, offcat, nullptr, BS * NQ, 768);

    // fused softmax + sampling + aggregation
    sample_kernel<<<dim3(BS * NQ), blk, 0, stream>>>(
        vproj, offcat, refpts, (float*)d_out);
}

// Round 4
// 224.985 us; speedup vs baseline: 2.0942x; 1.0123x over previous
//
#include <hip/hip_runtime.h>
#include <math.h>

#define NH 8
#define NL 4
#define NP 8
#define CDIM 256
#define NQ 10000
#define BS 2
#define NV 19560

__constant__ int LVL_H[NL]     = {92, 46, 23, 12};
__constant__ int LVL_W[NL]     = {160, 80, 40, 20};
__constant__ int LVL_START[NL] = {0, 14720, 18400, 19320};

typedef __attribute__((ext_vector_type(8))) short short8;
typedef __attribute__((ext_vector_type(4))) float f32x4;
typedef __attribute__((ext_vector_type(8))) _Float16 half8;

__device__ __forceinline__ unsigned short f2bf(float f) {
    unsigned int u = __float_as_uint(f);
    u += 0x7fffu + ((u >> 16) & 1u);   // RNE
    return (unsigned short)(u >> 16);
}

// ---------------------------------------------------------------------------
// fp32 -> bf16 bulk convert (A matrices). One float4 per thread.
// ---------------------------------------------------------------------------
__global__ __launch_bounds__(256) void cvt_bf16(
    const float* __restrict__ src, unsigned short* __restrict__ dst, int n4)
{
    const int i = blockIdx.x * 256 + threadIdx.x;
    if (i >= n4) return;
    const float4 f = ((const float4*)src)[i];
    ushort4 o;
    o.x = f2bf(f.x); o.y = f2bf(f.y); o.z = f2bf(f.z); o.w = f2bf(f.w);
    ((ushort4*)dst)[i] = o;
}

// ---------------------------------------------------------------------------
// Weights: transpose to [N][K] bf16; concat off|attn; build fp32 bias_cat.
// ---------------------------------------------------------------------------
__global__ __launch_bounds__(256) void prep_weights(
    const float* __restrict__ Wv,
    const float* __restrict__ Woff, const float* __restrict__ boff,
    const float* __restrict__ Wattn, const float* __restrict__ battn,
    unsigned short* __restrict__ BvalT, unsigned short* __restrict__ BcatT,
    float* __restrict__ biascat)
{
    const int n = blockIdx.x;
    const int t = threadIdx.x;
    if (n < 256) {
        BvalT[n * 256 + t] = f2bf(Wv[t * 256 + n]);
    } else if (n < 1024) {
        const int m = n - 256;
        const float v = (m < 512) ? Woff[t * 512 + m] : Wattn[t * 256 + (m - 512)];
        BcatT[m * 256 + t] = f2bf(v);
    } else {
        #pragma unroll
        for (int s = 0; s < 3; s++) {
            const int i = s * 256 + t;
            biascat[i] = (i < 512) ? boff[i] : battn[i - 512];
        }
    }
}

// ---------------------------------------------------------------------------
// bf16-MFMA GEMM, pre-converted bf16 A [M][256] and B^T [N][256].
// 128x128 tile, 256 threads, BK=32. All staging = 16B loads + ds_write_b128,
// zero conversions in the K-loop. f16 output.
// MODE 0: Ch[row*N+col]. MODE 1: head-major vproj (b, h, pix, 32).
// ---------------------------------------------------------------------------
#define AST 130
template <int MODE>
__global__ __launch_bounds__(256) void gemm_bias_mfma(
    const unsigned short* __restrict__ A, const unsigned short* __restrict__ Bt,
    const float* __restrict__ bias, _Float16* __restrict__ Ch, int M, int N)
{
    __shared__ short8 Al[4 * AST];
    __shared__ short8 Bl[4 * AST];

    const int t = threadIdx.x;
    const int rowBase = blockIdx.x * 128;
    const int colBase = blockIdx.y * 128;

    const int w  = t >> 6;            // wave 0..3
    const int l  = t & 63;
    const int wm = (w >> 1) * 64;
    const int wn = (w & 1) * 64;
    const int row16 = l & 15;
    const int kg    = l >> 4;

    // staging: thread covers tile row sr, k-half sh (16 bf16 = 2 x 16B loads)
    const int sr = t >> 1;
    const int sh = t & 1;

    f32x4 acc[4][4] = {};

    for (int k0 = 0; k0 < 256; k0 += 32) {
        {   // A tile
            const int grow = rowBase + sr;
            short8 v0 = {}, v1 = {};
            if (grow < M) {
                const unsigned short* ap = A + (size_t)grow * 256 + k0 + sh * 16;
                v0 = *(const short8*)ap;
                v1 = *(const short8*)(ap + 8);
            }
            Al[(sh * 2 + 0) * AST + sr] = v0;
            Al[(sh * 2 + 1) * AST + sr] = v1;
        }
        {   // B tile (B^T layout: same access pattern, cols always in-range)
            const unsigned short* bp = Bt + (size_t)(colBase + sr) * 256 + k0 + sh * 16;
            Bl[(sh * 2 + 0) * AST + sr] = *(const short8*)bp;
            Bl[(sh * 2 + 1) * AST + sr] = *(const short8*)(bp + 8);
        }
        __syncthreads();

        short8 af[4], bfr[4];
        #pragma unroll
        for (int i = 0; i < 4; i++) af[i] = Al[kg * AST + wm + i * 16 + row16];
        #pragma unroll
        for (int j = 0; j < 4; j++) bfr[j] = Bl[kg * AST + wn + j * 16 + row16];
        #pragma unroll
        for (int i = 0; i < 4; i++)
            #pragma unroll
            for (int j = 0; j < 4; j++)
                acc[i][j] = __builtin_amdgcn_mfma_f32_16x16x32_bf16(
                    af[i], bfr[j], acc[i][j], 0, 0, 0);
        __syncthreads();
    }

    // epilogue: C/D layout col = l&15, row = (l>>4)*4 + reg
    const int crow0 = rowBase + wm + (l >> 4) * 4;
    const int ccol0 = colBase + wn + (l & 15);
    float bv[4];
    #pragma unroll
    for (int j = 0; j < 4; j++) bv[j] = bias[ccol0 + j * 16];
    #pragma unroll
    for (int i = 0; i < 4; i++) {
        #pragma unroll
        for (int r = 0; r < 4; r++) {
            const int row = crow0 + i * 16 + r;
            if (row >= M) continue;
            #pragma unroll
            for (int j = 0; j < 4; j++) {
                const float val = acc[i][j][r] + bv[j];
                const int col = ccol0 + j * 16;
                if (MODE == 0) {
                    Ch[(size_t)row * N + col] = (_Float16)val;
                } else {
                    const int b   = row / NV;
                    const int pix = row - b * NV;
                    const int h   = col >> 5;
                    const int ch  = col & 31;
                    Ch[((size_t)(b * NH + h) * NV + pix) * 32 + ch] = (_Float16)val;
                }
            }
        }
    }
}

// ---------------------------------------------------------------------------
// Fused softmax + sampling + aggregation, (b,h)-partitioned for L2 locality.
// vproj is f16; inner loop uses  acc += w * (float)h  -> v_fma_mix_f32
// (no unpack ops).
// ---------------------------------------------------------------------------
__global__ __launch_bounds__(256) void sample_kernel(
    const _Float16* __restrict__ vproj,  // (BS, NH, NV, 32) f16
    const _Float16* __restrict__ offcat, // (BS*NQ, 768) f16 off|logits
    const float* __restrict__ refpts,    // (BS, NQ, 4, 2)
    float* __restrict__ out)             // (BS*NQ, 256)
{
    const int bid = blockIdx.x;
    const int h   = bid & 7;             // XCD-affine head
    const int g   = bid >> 3;
    const int b   = g & 1;
    const int q0  = (g >> 1) * 8;
    const int t   = threadIdx.x;

    __shared__ float4 desc[8 * 64];      // {idx(bits), wL, wR, pad}

    const int qi = t >> 5, j = t & 31;
    const int qrow = b * NQ + q0 + qi;

    // ---------------- Phase A ----------------
    {
        const int lv = j >> 3, p = j & 7;

        float logit = (float)offcat[(size_t)qrow * 768 + 512 + h * 32 + j];
        float m = logit;
        #pragma unroll
        for (int s = 16; s > 0; s >>= 1) m = fmaxf(m, __shfl_xor(m, s, 32));
        float e = __expf(logit - m);
        float ssum = e;
        #pragma unroll
        for (int s = 16; s > 0; s >>= 1) ssum += __shfl_xor(ssum, s, 32);
        const float aw = e / ssum;

        const int Wl = LVL_W[lv], Hl = LVL_H[lv], st = LVL_START[lv];
        const float offx = (float)offcat[(size_t)qrow * 768 + h * 64 + j * 2];
        const float offy = (float)offcat[(size_t)qrow * 768 + h * 64 + j * 2 + 1];

        const int z = p & 3;
        const float rx = refpts[((size_t)qrow * 4 + z) * 2];
        const float ry = refpts[((size_t)qrow * 4 + z) * 2 + 1];

        const float x = fmaf(rx, (float)Wl, offx) - 0.5f;
        const float y = fmaf(ry, (float)Hl, offy) - 0.5f;
        const float x0f = floorf(x), y0f = floorf(y);
        const float wx = x - x0f, wy = y - y0f;
        const int x0 = (int)x0f, y0 = (int)y0f;

        const int xb = min(max(x0, 0), Wl - 2);
        const float wl = (x0 >= 0 && x0 < Wl)          ? (1.f - wx) : 0.f;
        const float wr = (x0 + 1 >= 0 && x0 + 1 < Wl)  ? wx         : 0.f;
        const float wA = (x0 == xb) ? wl : ((x0 + 1 == xb) ? wr : 0.f);
        const float wB = (x0 == xb) ? wr : ((x0 == xb + 1) ? wl : 0.f);

        #pragma unroll
        for (int r = 0; r < 2; r++) {
            const int yy = y0 + r;
            const float rwv = (yy >= 0 && yy < Hl)
                            ? (r ? wy : (1.f - wy)) * aw : 0.f;
            const int iy = min(max(yy, 0), Hl - 1);
            float4 d;
            d.x = __int_as_float(st + iy * Wl + xb);
            d.y = wA * rwv;
            d.z = wB * rwv;
            d.w = 0.f;
            desc[qi * 64 + j * 2 + r] = d;
        }
    }
    __syncthreads();

    // ---------------- Phase B ----------------
    const int lane = t & 31;
    const int grp  = lane >> 3;          // descriptor stride group
    const int sub  = lane & 7;
    const int pix  = sub >> 2;           // left/right x-column
    const int chq  = sub & 3;            // channel quad (8 ch = 16 B)

    const _Float16* slab = vproj + (size_t)(b * NH + h) * NV * 32;
    const float4* dq = &desc[qi * 64];

    float acc[8] = {};
    #pragma unroll 4
    for (int i = 0; i < 16; i++) {
        const float4 dsc = dq[i * 4 + grp];
        const int   lidx = __float_as_int(dsc.x);
        const float w    = pix ? dsc.z : dsc.y;
        const half8 v = *(const half8*)(slab + (size_t)(lidx + pix) * 32 + chq * 8);
        #pragma unroll
        for (int e = 0; e < 8; e++)
            acc[e] += w * (float)v[e];   // v_fma_mix_f32
    }

    #pragma unroll
    for (int s = 4; s <= 16; s <<= 1)
        #pragma unroll
        for (int e = 0; e < 8; e++) acc[e] += __shfl_xor(acc[e], s, 32);

    if ((lane & 0x1C) == 0) {            // lanes 0..3 = chq
        float* op = out + (size_t)qrow * 256 + h * 32 + chq * 8;
        *(float4*)op       = make_float4(acc[0], acc[1], acc[2], acc[3]);
        *(float4*)(op + 4) = make_float4(acc[4], acc[5], acc[6], acc[7]);
    }
}

// ---------------------------------------------------------------------------
extern "C" void kernel_launch(void* const* d_in, const int* in_sizes, int n_in,
                              void* d_out, int out_size, void* d_ws, size_t ws_size,
                              hipStream_t stream)
{
    const float* query   = (const float*)d_in[0];
    const float* value   = (const float*)d_in[1];
    const float* refpts  = (const float*)d_in[2];
    const float* W_value = (const float*)d_in[4];
    const float* b_value = (const float*)d_in[5];
    const float* W_off   = (const float*)d_in[6];
    const float* b_off   = (const float*)d_in[7];
    const float* W_attn  = (const float*)d_in[8];
    const float* b_attn  = (const float*)d_in[9];

    char* ws = (char*)d_ws;                       // total 81.55 MB
    _Float16*       vproj   = (_Float16*)(ws);                    // 20,029,440
    unsigned short* valuebf = (unsigned short*)(ws + 20029440);   // 20,029,440
    unsigned short* querybf = (unsigned short*)(ws + 40058880);   // 10,240,000
    _Float16*       offcat  = (_Float16*)(ws + 50298880);         // 30,720,000
    unsigned short* BvalT   = (unsigned short*)(ws + 81018880);   //    131,072
    unsigned short* BcatT   = (unsigned short*)(ws + 81149952);   //    393,216
    float*          biascat = (float*)(ws + 81543168);            //      3,072

    const dim3 blk(256);

    // prep: bulk bf16 conversions + weight transpose/concat
    cvt_bf16<<<dim3(9780), blk, 0, stream>>>(value, valuebf, BS * NV * 256 / 4);
    cvt_bf16<<<dim3(5000), blk, 0, stream>>>(query, querybf, BS * NQ * 256 / 4);
    prep_weights<<<dim3(1025), blk, 0, stream>>>(W_value, W_off, b_off,
                                                 W_attn, b_attn,
                                                 BvalT, BcatT, biascat);

    // value projection -> f16 head-major vproj
    gemm_bias_mfma<1><<<dim3((BS * NV + 127) / 128, 2), blk, 0, stream>>>(
        valuebf, BvalT, b_value, vproj, BS * NV, CDIM);

    // fused offsets+logits: (20000 x 256) @ (256 x 768) -> f16
    gemm_bias_mfma<0><<<dim3((BS * NQ + 127) / 128, 6), blk, 0, stream>>>(
        querybf, BcatT, biascat, offcat, BS * NQ, 768);

    // fused softmax + sampling + aggregation
    sample_kernel<<<dim3(BS * NQ), blk, 0, stream>>>(
        vproj, offcat, refpts, (float*)d_out);
}

// Round 5
// 214.906 us; speedup vs baseline: 2.1924x; 1.0469x over previous
//
#include <hip/hip_runtime.h>
#include <math.h>

#define NH 8
#define NL 4
#define NP 8
#define CDIM 256
#define NQ 10000
#define BS 2
#define NV 19560

__constant__ int LVL_H[NL]     = {92, 46, 23, 12};
__constant__ int LVL_W[NL]     = {160, 80, 40, 20};
__constant__ int LVL_START[NL] = {0, 14720, 18400, 19320};

typedef __attribute__((ext_vector_type(8))) short short8;
typedef __attribute__((ext_vector_type(4))) float f32x4;
typedef __attribute__((ext_vector_type(2))) _Float16 half2v;
typedef __attribute__((ext_vector_type(4))) _Float16 half4v;

__device__ __forceinline__ unsigned short f2bf(float f) {
    unsigned int u = __float_as_uint(f);
    u += 0x7fffu + ((u >> 16) & 1u);   // RNE
    return (unsigned short)(u >> 16);
}

// ---------------------------------------------------------------------------
// All prep in ONE dispatch: value->bf16, query->bf16, weight transpose/concat.
// blocks [0,9780): value; [9780,14780): query; [14780,15805): weights/bias.
// ---------------------------------------------------------------------------
__global__ __launch_bounds__(256) void prep_all(
    const float* __restrict__ value, const float* __restrict__ query,
    const float* __restrict__ Wv,
    const float* __restrict__ Woff, const float* __restrict__ boff,
    const float* __restrict__ Wattn, const float* __restrict__ battn,
    unsigned short* __restrict__ valuebf, unsigned short* __restrict__ querybf,
    unsigned short* __restrict__ BvalT, unsigned short* __restrict__ BcatT,
    float* __restrict__ biascat)
{
    const int bid = blockIdx.x;
    const int t   = threadIdx.x;
    if (bid < 9780) {
        const int i = bid * 256 + t;
        const float4 f = ((const float4*)value)[i];
        ushort4 o;
        o.x = f2bf(f.x); o.y = f2bf(f.y); o.z = f2bf(f.z); o.w = f2bf(f.w);
        ((ushort4*)valuebf)[i] = o;
    } else if (bid < 14780) {
        const int i = (bid - 9780) * 256 + t;
        const float4 f = ((const float4*)query)[i];
        ushort4 o;
        o.x = f2bf(f.x); o.y = f2bf(f.y); o.z = f2bf(f.z); o.w = f2bf(f.w);
        ((ushort4*)querybf)[i] = o;
    } else {
        const int n = bid - 14780;
        if (n < 256) {
            BvalT[n * 256 + t] = f2bf(Wv[t * 256 + n]);
        } else if (n < 1024) {
            const int m = n - 256;
            const float v = (m < 512) ? Woff[t * 512 + m]
                                      : Wattn[t * 256 + (m - 512)];
            BcatT[m * 256 + t] = f2bf(v);
        } else {
            #pragma unroll
            for (int s = 0; s < 3; s++) {
                const int i = s * 256 + t;
                biascat[i] = (i < 512) ? boff[i] : battn[i - 512];
            }
        }
    }
}

// ---------------------------------------------------------------------------
// BOTH GEMMs in one dispatch. bf16 A [M][256], B^T [N][256], BK=32,
// 128x128 tile. MFMA operands SWAPPED -> reg quad holds 4 consecutive
// COLUMNS: epilogue is 8B-contiguous f16 stores (no 2B scatter).
// blocks [0,612): value proj -> head-major f16 vproj (b,h,pix,32)
// blocks [612,1554): query @ Wcat -> f16 offcat (row,768)
// ---------------------------------------------------------------------------
#define AST 130
__global__ __launch_bounds__(256) void gemm_all(
    const unsigned short* __restrict__ valuebf,
    const unsigned short* __restrict__ BvalT,
    const float* __restrict__ b_value, _Float16* __restrict__ vproj,
    const unsigned short* __restrict__ querybf,
    const unsigned short* __restrict__ BcatT,
    const float* __restrict__ biascat, _Float16* __restrict__ offcat)
{
    __shared__ short8 Al[4 * AST];
    __shared__ short8 Bl[4 * AST];

    const int bid = blockIdx.x;
    const bool modeV = bid < 612;

    const unsigned short* A;
    const unsigned short* Bt;
    const float* bias;
    int M, N, rowBase, colBase;
    if (modeV) {
        A = valuebf; Bt = BvalT; bias = b_value;
        M = BS * NV; N = 256;
        rowBase = (bid >> 1) * 128; colBase = (bid & 1) * 128;
    } else {
        const int b2 = bid - 612;
        A = querybf; Bt = BcatT; bias = biascat;
        M = BS * NQ; N = 768;
        rowBase = (b2 / 6) * 128; colBase = (b2 % 6) * 128;
    }

    const int t = threadIdx.x;
    const int w  = t >> 6;
    const int l  = t & 63;
    const int wm = (w >> 1) * 64;
    const int wn = (w & 1) * 64;
    const int row16 = l & 15;
    const int kg    = l >> 4;

    const int sr = t >> 1;
    const int sh = t & 1;

    f32x4 acc[4][4] = {};

    for (int k0 = 0; k0 < 256; k0 += 32) {
        {   // A tile
            const int grow = rowBase + sr;
            short8 v0 = {}, v1 = {};
            if (grow < M) {
                const unsigned short* ap = A + (size_t)grow * 256 + k0 + sh * 16;
                v0 = *(const short8*)ap;
                v1 = *(const short8*)(ap + 8);
            }
            Al[(sh * 2 + 0) * AST + sr] = v0;
            Al[(sh * 2 + 1) * AST + sr] = v1;
        }
        {   // B tile (B^T: always in-range)
            const unsigned short* bp = Bt + (size_t)(colBase + sr) * 256 + k0 + sh * 16;
            Bl[(sh * 2 + 0) * AST + sr] = *(const short8*)bp;
            Bl[(sh * 2 + 1) * AST + sr] = *(const short8*)(bp + 8);
        }
        __syncthreads();

        short8 af[4], bfr[4];
        #pragma unroll
        for (int i = 0; i < 4; i++) af[i] = Al[kg * AST + wm + i * 16 + row16];
        #pragma unroll
        for (int j = 0; j < 4; j++) bfr[j] = Bl[kg * AST + wn + j * 16 + row16];
        // swapped operands: D "row" = col-of-C, reg quad = 4 consecutive cols
        #pragma unroll
        for (int i = 0; i < 4; i++)
            #pragma unroll
            for (int j = 0; j < 4; j++)
                acc[i][j] = __builtin_amdgcn_mfma_f32_16x16x32_bf16(
                    bfr[j], af[i], acc[i][j], 0, 0, 0);
        __syncthreads();
    }

    // epilogue (swapped layout): row = base + i*16 + (l&15),
    //                            col = base + j*16 + (l>>4)*4 + reg
    const int m16 = l & 15;
    const int q4  = (l >> 4) * 4;
    #pragma unroll
    for (int i = 0; i < 4; i++) {
        const int row = rowBase + wm + i * 16 + m16;
        if (row >= M) continue;
        #pragma unroll
        for (int j = 0; j < 4; j++) {
            const int col0 = colBase + wn + j * 16 + q4;
            const float4 bv = *(const float4*)&bias[col0];
            half4v o;
            o[0] = (_Float16)(acc[i][j][0] + bv.x);
            o[1] = (_Float16)(acc[i][j][1] + bv.y);
            o[2] = (_Float16)(acc[i][j][2] + bv.z);
            o[3] = (_Float16)(acc[i][j][3] + bv.w);
            _Float16* dst;
            if (modeV) {
                const int b   = (row >= NV) ? 1 : 0;
                const int pix = row - b * NV;
                const int h   = col0 >> 5;
                const int ch  = col0 & 31;
                dst = vproj + ((size_t)(b * NH + h) * NV + pix) * 32 + ch;
            } else {
                dst = offcat + (size_t)row * 768 + col0;
            }
            *(half4v*)dst = o;
        }
    }
}

// ---------------------------------------------------------------------------
// Fused softmax + sampling + aggregation, (b,h)-partitioned for L2 locality.
// Phase B inner loop: uint4 load + 4 v_pk_fma_f16 (f16 accumulate),
// f32 cross-lane reduce.
// ---------------------------------------------------------------------------
__global__ __launch_bounds__(256) void sample_kernel(
    const _Float16* __restrict__ vproj,  // (BS, NH, NV, 32) f16
    const _Float16* __restrict__ offcat, // (BS*NQ, 768) f16 off|logits
    const float* __restrict__ refpts,    // (BS, NQ, 4, 2)
    float* __restrict__ out)             // (BS*NQ, 256)
{
    const int bid = blockIdx.x;
    const int h   = bid & 7;             // XCD-affine head
    const int g   = bid >> 3;
    const int b   = g & 1;
    const int q0  = (g >> 1) * 8;
    const int t   = threadIdx.x;

    __shared__ float4 desc[8 * 64];      // {idx(bits), wL, wR, pad}

    const int qi = t >> 5, j = t & 31;
    const int qrow = b * NQ + q0 + qi;

    // ---------------- Phase A ----------------
    {
        const int lv = j >> 3, p = j & 7;

        float logit = (float)offcat[(size_t)qrow * 768 + 512 + h * 32 + j];
        float m = logit;
        #pragma unroll
        for (int s = 16; s > 0; s >>= 1) m = fmaxf(m, __shfl_xor(m, s, 32));
        float e = __expf(logit - m);
        float ssum = e;
        #pragma unroll
        for (int s = 16; s > 0; s >>= 1) ssum += __shfl_xor(ssum, s, 32);
        const float aw = e / ssum;

        const int Wl = LVL_W[lv], Hl = LVL_H[lv], st = LVL_START[lv];
        const float offx = (float)offcat[(size_t)qrow * 768 + h * 64 + j * 2];
        const float offy = (float)offcat[(size_t)qrow * 768 + h * 64 + j * 2 + 1];

        const int z = p & 3;
        const float rx = refpts[((size_t)qrow * 4 + z) * 2];
        const float ry = refpts[((size_t)qrow * 4 + z) * 2 + 1];

        const float x = fmaf(rx, (float)Wl, offx) - 0.5f;
        const float y = fmaf(ry, (float)Hl, offy) - 0.5f;
        const float x0f = floorf(x), y0f = floorf(y);
        const float wx = x - x0f, wy = y - y0f;
        const int x0 = (int)x0f, y0 = (int)y0f;

        const int xb = min(max(x0, 0), Wl - 2);
        const float wl = (x0 >= 0 && x0 < Wl)          ? (1.f - wx) : 0.f;
        const float wr = (x0 + 1 >= 0 && x0 + 1 < Wl)  ? wx         : 0.f;
        const float wA = (x0 == xb) ? wl : ((x0 + 1 == xb) ? wr : 0.f);
        const float wB = (x0 == xb) ? wr : ((x0 == xb + 1) ? wl : 0.f);

        #pragma unroll
        for (int r = 0; r < 2; r++) {
            const int yy = y0 + r;
            const float rwv = (yy >= 0 && yy < Hl)
                            ? (r ? wy : (1.f - wy)) * aw : 0.f;
            const int iy = min(max(yy, 0), Hl - 1);
            float4 d;
            d.x = __int_as_float(st + iy * Wl + xb);
            d.y = wA * rwv;
            d.z = wB * rwv;
            d.w = 0.f;
            desc[qi * 64 + j * 2 + r] = d;
        }
    }
    __syncthreads();

    // ---------------- Phase B ----------------
    const int lane = t & 31;
    const int grp  = lane >> 3;          // descriptor stride group
    const int sub  = lane & 7;
    const int pix  = sub >> 2;           // left/right x-column
    const int chq  = sub & 3;            // channel quad (8 ch = 16 B)

    const _Float16* slab = vproj + (size_t)(b * NH + h) * NV * 32 + chq * 8;
    const float4* dq = &desc[qi * 64];

    half2v a0 = {}, a1 = {}, a2 = {}, a3 = {};
    #pragma unroll 8
    for (int i = 0; i < 16; i++) {
        const float4 dsc = dq[i * 4 + grp];
        const int   lidx = __float_as_int(dsc.x);
        const float w    = pix ? dsc.z : dsc.y;
        const _Float16 wh = (_Float16)w;
        half2v wv; wv[0] = wh; wv[1] = wh;
        const uint4 u = *(const uint4*)(slab + (size_t)(lidx + pix) * 32);
        a0 += wv * __builtin_bit_cast(half2v, u.x);   // v_pk_fma_f16
        a1 += wv * __builtin_bit_cast(half2v, u.y);
        a2 += wv * __builtin_bit_cast(half2v, u.z);
        a3 += wv * __builtin_bit_cast(half2v, u.w);
    }

    float accf[8] = {(float)a0[0], (float)a0[1], (float)a1[0], (float)a1[1],
                     (float)a2[0], (float)a2[1], (float)a3[0], (float)a3[1]};
    #pragma unroll
    for (int s = 4; s <= 16; s <<= 1)
        #pragma unroll
        for (int e = 0; e < 8; e++) accf[e] += __shfl_xor(accf[e], s, 32);

    if ((lane & 0x1C) == 0) {            // lanes 0..3 = chq
        float* op = out + (size_t)qrow * 256 + h * 32 + chq * 8;
        *(float4*)op       = make_float4(accf[0], accf[1], accf[2], accf[3]);
        *(float4*)(op + 4) = make_float4(accf[4], accf[5], accf[6], accf[7]);
    }
}

// ---------------------------------------------------------------------------
extern "C" void kernel_launch(void* const* d_in, const int* in_sizes, int n_in,
                              void* d_out, int out_size, void* d_ws, size_t ws_size,
                              hipStream_t stream)
{
    const float* query   = (const float*)d_in[0];
    const float* value   = (const float*)d_in[1];
    const float* refpts  = (const float*)d_in[2];
    const float* W_value = (const float*)d_in[4];
    const float* b_value = (const float*)d_in[5];
    const float* W_off   = (const float*)d_in[6];
    const float* b_off   = (const float*)d_in[7];
    const float* W_attn  = (const float*)d_in[8];
    const float* b_attn  = (const float*)d_in[9];

    char* ws = (char*)d_ws;                       // total 81.55 MB
    _Float16*       vproj   = (_Float16*)(ws);                    // 20,029,440
    unsigned short* valuebf = (unsigned short*)(ws + 20029440);   // 20,029,440
    unsigned short* querybf = (unsigned short*)(ws + 40058880);   // 10,240,000
    _Float16*       offcat  = (_Float16*)(ws + 50298880);         // 30,720,000
    unsigned short* BvalT   = (unsigned short*)(ws + 81018880);   //    131,072
    unsigned short* BcatT   = (unsigned short*)(ws + 81149952);   //    393,216
    float*          biascat = (float*)(ws + 81543168);            //      3,072

    const dim3 blk(256);

    prep_all<<<dim3(15805), blk, 0, stream>>>(
        value, query, W_value, W_off, b_off, W_attn, b_attn,
        valuebf, querybf, BvalT, BcatT, biascat);

    gemm_all<<<dim3(1554), blk, 0, stream>>>(
        valuebf, BvalT, b_value, vproj,
        querybf, BcatT, biascat, offcat);

    sample_kernel<<<dim3(BS * NQ), blk, 0, stream>>>(
        vproj, offcat, refpts, (float*)d_out);
}